// Round 3
// baseline (33.625 us; speedup 1.0000x reference)
//
#include <hip/hip_runtime.h>
#include <stdint.h>

#define NR 5000
#define NRM1 4999
#define W 640
#define NPAIRS 2500        // balanced row pairs: pair rp = rows {rp, 4998-rp}, 5000 elems
#define NBLK 640           // grid-stride over row pairs: ~4 pairs (20K elems) per block
#define PCOUNT 12497500.0f

// ---------------- Kernel 1: gather z = x[rows, cols] ----------------
__global__ void gather_z(const float* __restrict__ x,
                         const int* __restrict__ centers,
                         float* __restrict__ z) {
    int t = blockIdx.x * blockDim.x + threadIdx.x;
    if (t < NR) {
        int r = centers[2 * t];
        int c = centers[2 * t + 1];
        z[t] = x[r * W + c];
    }
}

// softplus(-g*d) when g=+-1, else d^2.  Hardware trans pipe: v_exp_f32+v_log_f32.
// |d| <= ~10 so exp never overflows; g==0 path computes log(2) harmlessly then selects d*d.
__device__ __forceinline__ float loss_elem(float zr, float zj, float g) {
    float d = zr - zj;
    float sp = __logf(1.0f + __expf(-g * d));
    return (g != 0.0f) ? sp : d * d;
}

// Sum of loss over one triu row r (len elems), cooperatively across the block.
// gt row pointer is peeled to 16B alignment; body uses float4 loads (16B/lane).
// z reads are scalar: all of z (20KB) is L1-resident.
__device__ __forceinline__ float row_sum(const float* __restrict__ gtr,
                                         const float* __restrict__ zrow,
                                         float zr, int len, int tid) {
    float acc = 0.0f;
    int head = (4 - (int)(((uintptr_t)gtr >> 2) & 3)) & 3;
    if (head > len) head = len;
    if (tid < head) acc += loss_elem(zr, zrow[tid], gtr[tid]);

    const int body = (len - head) & ~3;
    const int nv = body >> 2;
    const float4* __restrict__ gv = (const float4*)(gtr + head);
    const float* __restrict__ zb = zrow + head;
    for (int v = tid; v < nv; v += 256) {
        const float4 g = gv[v];
        const int base = 4 * v;
        float a = loss_elem(zr, zb[base + 0], g.x);
        float b = loss_elem(zr, zb[base + 1], g.y);
        float c = loss_elem(zr, zb[base + 2], g.z);
        float d = loss_elem(zr, zb[base + 3], g.w);
        acc += (a + b) + (c + d);
    }

    const int ti = head + body + tid;
    if (ti < len) acc += loss_elem(zr, zrow[ti], gtr[ti]);
    return acc;
}

// ---------------- Kernel 2: per-pair loss, per-block partial sums ----------------
__global__ __launch_bounds__(256) void pair_loss(const float* __restrict__ gt,
                                                 const float* __restrict__ z,
                                                 float* __restrict__ partials) {
    __shared__ float wsum[4];
    const int tid = threadIdx.x;
    float acc = 0.0f;

    for (int rp = blockIdx.x; rp < NPAIRS; rp += NBLK) {
        {   // row r1 = rp, len 4999-rp
            const int r = rp;
            const int off = r * NRM1 - (r * (r - 1)) / 2;
            acc += row_sum(gt + off, z + r + 1, z[r], NRM1 - r, tid);
        }
        const int r2 = NR - 2 - rp;
        if (r2 > rp) {  // row r2, len rp+1
            const int off = r2 * NRM1 - (r2 * (r2 - 1)) / 2;
            acc += row_sum(gt + off, z + r2 + 1, z[r2], NRM1 - r2, tid);
        }
    }

    // deterministic block reduction: wave shuffle tree + LDS across 4 waves
    for (int o = 32; o > 0; o >>= 1) acc += __shfl_down(acc, o, 64);
    const int wid = tid >> 6;
    const int lane = tid & 63;
    if (lane == 0) wsum[wid] = acc;
    __syncthreads();
    if (tid == 0)
        partials[blockIdx.x] = (wsum[0] + wsum[1]) + (wsum[2] + wsum[3]);
}

// ---------------- Kernel 3: deterministic final reduce ----------------
__global__ __launch_bounds__(256) void final_reduce(const float* __restrict__ partials,
                                                    float* __restrict__ out) {
    __shared__ float wsum[4];
    float acc = 0.0f;
    for (int t = threadIdx.x; t < NBLK; t += 256) acc += partials[t];
    for (int o = 32; o > 0; o >>= 1) acc += __shfl_down(acc, o, 64);
    const int wid = threadIdx.x >> 6;
    const int lane = threadIdx.x & 63;
    if (lane == 0) wsum[wid] = acc;
    __syncthreads();
    if (threadIdx.x == 0)
        out[0] = ((wsum[0] + wsum[1]) + (wsum[2] + wsum[3])) / PCOUNT;
}

extern "C" void kernel_launch(void* const* d_in, const int* in_sizes, int n_in,
                              void* d_out, int out_size, void* d_ws, size_t ws_size,
                              hipStream_t stream) {
    const float* x       = (const float*)d_in[0];   // (480,640) f32
    const float* gt      = (const float*)d_in[1];   // (P,) f32
    const int*   centers = (const int*)d_in[2];     // (5000,2) int32
    float* out = (float*)d_out;                     // scalar f32

    float* z        = (float*)d_ws;                 // 5000 floats
    float* partials = z + NR;                       // NBLK floats

    gather_z<<<(NR + 255) / 256, 256, 0, stream>>>(x, centers, z);
    pair_loss<<<NBLK, 256, 0, stream>>>(gt, z, partials);
    final_reduce<<<1, 256, 0, stream>>>(partials, out);
}

// Round 5
// 26.749 us; speedup vs baseline: 1.2571x; 1.2571x over previous
//
#include <hip/hip_runtime.h>
#include <stdint.h>

#define NR 5000
#define NRM1 4999
#define W 640
#define NBLK 2500          // block-per-pair: block b handles rows b and 4998-b (5000 elems)
#define PCOUNT 12497500.0f
#define LOG2E 1.44269504088896340736f
#define LN2   0.69314718055994530942f

// ---------------- Kernel 1: gather z = x[rows, cols] ----------------
__global__ void gather_z(const float* __restrict__ x,
                         const int* __restrict__ centers,
                         float* __restrict__ z) {
    int t = blockIdx.x * blockDim.x + threadIdx.x;
    if (t < NR) {
        int r = centers[2 * t];
        int c = centers[2 * t + 1];
        z[t] = x[r * W + c];
    }
}

// Per-element loss in log2 domain (final result multiplied by ln2 in final_reduce):
//   g != 0 : log2(1 + 2^(-g*d*log2e))        [= softplus(-g*d)/ln2]
//   g == 0 : d * (d*log2e)                    [= d^2/ln2]
// dl = d*log2e is shared by both paths. exp2f/__log2f lower to native v_exp_f32/v_log_f32.
__device__ __forceinline__ float loss2(float zr, float zj, float g) {
    const float d  = zr - zj;
    const float dl = d * LOG2E;
    const float lg = __log2f(1.0f + exp2f(-g * dl));
    return (g != 0.0f) ? lg : d * dl;
}

// Sum over one triu row (len elems) cooperatively across 256 threads.
// gt row is peeled to 16B alignment, body uses float4 (16B/lane); z reads are
// scalar (z is 20KB, L1-resident).
__device__ __forceinline__ float row_sum(const float* __restrict__ gtr,
                                         const float* __restrict__ zrow,
                                         float zr, int len, int tid) {
    int head = (int)((0u - (uint32_t)(((uintptr_t)gtr) >> 2)) & 3u);
    if (head > len) head = len;
    float a0 = 0.0f, a1 = 0.0f, a2 = 0.0f, a3 = 0.0f;
    if (tid < head) a0 += loss2(zr, zrow[tid], gtr[tid]);

    const int nv = (len - head) >> 2;
    const float4* __restrict__ gv = (const float4*)(gtr + head);
    const float* __restrict__ zb = zrow + head;
    for (int v = tid; v < nv; v += 256) {
        const float4 g = gv[v];
        const int base = 4 * v;
        a0 += loss2(zr, zb[base + 0], g.x);
        a1 += loss2(zr, zb[base + 1], g.y);
        a2 += loss2(zr, zb[base + 2], g.z);
        a3 += loss2(zr, zb[base + 3], g.w);
    }

    const int ti = head + 4 * nv + tid;
    if (ti < len) a1 += loss2(zr, zrow[ti], gtr[ti]);
    return (a0 + a1) + (a2 + a3);
}

// ---------------- Kernel 2: per-pair loss, per-block partial sums ----------------
__global__ __launch_bounds__(256) void pair_loss(const float* __restrict__ gt,
                                                 const float* __restrict__ z,
                                                 float* __restrict__ partials) {
    __shared__ float wsum[4];
    const int tid = threadIdx.x;
    const int b = blockIdx.x;
    float acc = 0.0f;

    {   // row r1 = b, len 4999-b
        const int r = b;
        const int off = r * NRM1 - (r * (r - 1)) / 2;   // fits i32
        acc += row_sum(gt + off, z + r + 1, z[r], NRM1 - r, tid);
    }
    const int r2 = NR - 2 - b;
    if (r2 > b) {  // row r2, len b+1
        const int off = r2 * NRM1 - (r2 * (r2 - 1)) / 2;
        acc += row_sum(gt + off, z + r2 + 1, z[r2], NRM1 - r2, tid);
    }

    // deterministic block reduction: wave shuffle tree + LDS across 4 waves
    for (int o = 32; o > 0; o >>= 1) acc += __shfl_down(acc, o, 64);
    const int wid = tid >> 6;
    const int lane = tid & 63;
    if (lane == 0) wsum[wid] = acc;
    __syncthreads();
    if (tid == 0)
        partials[b] = (wsum[0] + wsum[1]) + (wsum[2] + wsum[3]);
}

// ---------------- Kernel 3: deterministic final reduce (applies ln2/P) ----------------
__global__ __launch_bounds__(256) void final_reduce(const float* __restrict__ partials,
                                                    float* __restrict__ out) {
    __shared__ float wsum[4];
    float acc = 0.0f;
    for (int t = threadIdx.x; t < NBLK; t += 256) acc += partials[t];
    for (int o = 32; o > 0; o >>= 1) acc += __shfl_down(acc, o, 64);
    const int wid = threadIdx.x >> 6;
    const int lane = threadIdx.x & 63;
    if (lane == 0) wsum[wid] = acc;
    __syncthreads();
    if (threadIdx.x == 0)
        out[0] = ((wsum[0] + wsum[1]) + (wsum[2] + wsum[3])) * (LN2 / PCOUNT);
}

extern "C" void kernel_launch(void* const* d_in, const int* in_sizes, int n_in,
                              void* d_out, int out_size, void* d_ws, size_t ws_size,
                              hipStream_t stream) {
    const float* x       = (const float*)d_in[0];   // (480,640) f32
    const float* gt      = (const float*)d_in[1];   // (P,) f32
    const int*   centers = (const int*)d_in[2];     // (5000,2) int32
    float* out = (float*)d_out;                     // scalar f32

    float* z        = (float*)d_ws;                 // 5000 floats
    float* partials = z + NR;                       // NBLK floats

    gather_z<<<(NR + 255) / 256, 256, 0, stream>>>(x, centers, z);
    pair_loss<<<NBLK, 256, 0, stream>>>(gt, z, partials);
    final_reduce<<<1, 256, 0, stream>>>(partials, out);
}